// Round 1
// 175.226 us; speedup vs baseline: 1.0766x; 1.0766x over previous
//
#include <hip/hip_runtime.h>

#define H 1024
#define HH (H * H)          // 1048576 per channel plane
#define CHW (3 * HH)        // 3145728 per image
#define NB 256
#define HIST_BLOCKS 768     // exactly 3 blocks/CU on 256 CUs (784 left 16 CUs with a 4th block: +10us tail)
#define FIN_BLOCKS 512      // 2 blocks/CU x 6 waves = 12 waves/CU for the streaming pass

__device__ __forceinline__ float clamp01(float x) { return fminf(fmaxf(x, 0.0f), 1.0f); }

// bin of a value already divided by 255 (v01 = masked_value/255, mask in {0,1})
// (int)(v01*255) is bit-exact vs reference's (int)(clamp01(..)*255*mask).
__device__ __forceinline__ unsigned int bin8(float v01) {
    int b = (int)(v01 * 255.0f);
    return (unsigned int)min(max(b, 0), NB - 1);
}

// ---------------------------------------------------------------------------
// Stage 1: elementwise masking + packed per-pixel bin triples.
// R9 change: NO out3 copy anymore (k_finalize produces out3 densely).
// Block 0 zeroes ghist[1536] + loss; blocks 1..32 zero the 128KB scatter
// bitmap (kernel-boundary ordering guarantees visibility to k_hist).
// ---------------------------------------------------------------------------
__global__ void k_elementwise(const float4* __restrict__ inp,
                              const float4* __restrict__ tar,
                              const float4* __restrict__ rfp,
                              const float4* __restrict__ msrc,
                              const float4* __restrict__ mtar,
                              float4* __restrict__ out0, float4* __restrict__ out1,
                              float4* __restrict__ out2,
                              uint4* __restrict__ pk_dst, uint4* __restrict__ pk_ref,
                              unsigned int* __restrict__ gz,
                              unsigned int* __restrict__ bm,
                              float* __restrict__ loss)
{
    if (blockIdx.x == 0) {
        for (int i = threadIdx.x; i < 1536; i += blockDim.x) gz[i] = 0u;  // ghist
        if (threadIdx.x == 0) *loss = 0.0f;
    } else if (blockIdx.x <= 32) {
        int base = (int)(blockIdx.x - 1) * 1024;
        for (int i = threadIdx.x; i < 1024; i += blockDim.x) bm[base + i] = 0u;  // bitmap
    }
    int p = blockIdx.x * blockDim.x + threadIdx.x;
    if (p >= HH / 4) return;
    float4 ms4 = msrc[p], mt4 = mtar[p];
    // true division: 255.0f/255.0f == 1.0f exactly
    float msx = ms4.x / 255.0f, msy = ms4.y / 255.0f, msz = ms4.z / 255.0f, msw = ms4.w / 255.0f;
    float mtx = mt4.x / 255.0f, mty = mt4.y / 255.0f, mtz = mt4.z / 255.0f, mtw = mt4.w / 255.0f;
    unsigned int bd0 = 0, bd1 = 0, bd2 = 0, bd3 = 0;
    unsigned int br0 = 0, br1 = 0, br2 = 0, br3 = 0;
#pragma unroll
    for (int c = 0; c < 3; ++c) {
        int q = c * (HH / 4) + p;
        float4 t = tar[q], r = rfp[q], iv = inp[q];
        float4 o0, o1, o2;
        o0.x = clamp01((t.x + 1.0f) * 0.5f) * mtx;
        o0.y = clamp01((t.y + 1.0f) * 0.5f) * mty;
        o0.z = clamp01((t.z + 1.0f) * 0.5f) * mtz;
        o0.w = clamp01((t.w + 1.0f) * 0.5f) * mtw;
        o1.x = clamp01((r.x + 1.0f) * 0.5f) * msx;
        o1.y = clamp01((r.y + 1.0f) * 0.5f) * msy;
        o1.z = clamp01((r.z + 1.0f) * 0.5f) * msz;
        o1.w = clamp01((r.w + 1.0f) * 0.5f) * msw;
        o2.x = clamp01(iv.x) * msx;
        o2.y = clamp01(iv.y) * msy;
        o2.z = clamp01(iv.z) * msz;
        o2.w = clamp01(iv.w) * msw;
        out0[q] = o0;
        out1[q] = o1;
        out2[q] = o2;
        int sh = 8 * c;
        bd0 |= bin8(o1.x) << sh;  bd1 |= bin8(o1.y) << sh;
        bd2 |= bin8(o1.z) << sh;  bd3 |= bin8(o1.w) << sh;
        br0 |= bin8(o0.x) << sh;  br1 |= bin8(o0.y) << sh;
        br2 |= bin8(o0.z) << sh;  br3 |= bin8(o0.w) << sh;
    }
    pk_dst[p] = make_uint4(bd0, bd1, bd2, bd3);
    pk_ref[p] = make_uint4(br0, br1, br2, br3);
}

// ---------------------------------------------------------------------------
// Stage 2: histograms from packed bins + scatter-pixel bitmap mark.
// The mark (atomicOr, idempotent -> dedups duplicate indices for free) reuses
// pd which is already computed for the gather; fire-and-forget, hides under
// the gather latency. Ballot aggregation for fully-zero packed values as
// before (~30% of samples are masked-out).
// ---------------------------------------------------------------------------
__global__ void k_hist(const unsigned int* __restrict__ pk_dst,
                       const unsigned int* __restrict__ pk_ref,
                       const int* __restrict__ i0, const int* __restrict__ i1,
                       const int* __restrict__ i2, const int* __restrict__ i3,
                       unsigned int* __restrict__ ghist,
                       unsigned int* __restrict__ bm, int n)
{
    __shared__ unsigned int h[2 * 3 * NB];
    for (int i = threadIdx.x; i < 2 * 3 * NB; i += blockDim.x) h[i] = 0u;
    __syncthreads();

    int lane = threadIdx.x & 63;
    for (int k = blockIdx.x * blockDim.x + threadIdx.x; k < n; k += gridDim.x * blockDim.x) {
        int pd = i0[k] * H + i1[k];
        int pr = i2[k] * H + i3[k];
        unsigned int a = pk_dst[pd];
        unsigned int b = pk_ref[pr];

        atomicOr(&bm[(unsigned int)pd >> 5], 1u << (pd & 31));

        unsigned long long mza = __ballot(a == 0u);
        if (a != 0u) {
            atomicAdd(&h[        (a       & 255u)], 1u);
            atomicAdd(&h[  NB + ((a >> 8) & 255u)], 1u);
            atomicAdd(&h[2*NB + ((a >>16) & 255u)], 1u);
        } else if (lane == __ffsll(mza) - 1) {
            unsigned int cnt = (unsigned int)__popcll(mza);
            atomicAdd(&h[0],      cnt);
            atomicAdd(&h[NB],     cnt);
            atomicAdd(&h[2 * NB], cnt);
        }

        unsigned long long mzb = __ballot(b == 0u);
        if (b != 0u) {
            atomicAdd(&h[3*NB + ( b       & 255u)], 1u);
            atomicAdd(&h[4*NB + ((b >> 8) & 255u)], 1u);
            atomicAdd(&h[5*NB + ((b >>16) & 255u)], 1u);
        } else if (lane == __ffsll(mzb) - 1) {
            unsigned int cnt = (unsigned int)__popcll(mzb);
            atomicAdd(&h[3 * NB], cnt);
            atomicAdd(&h[4 * NB], cnt);
            atomicAdd(&h[5 * NB], cnt);
        }
    }
    __syncthreads();
    for (int i = threadIdx.x; i < 2 * 3 * NB; i += blockDim.x) {
        unsigned int v = h[i];
        if (v) atomicAdd(&ghist[i], v);
    }
}

// ---------------------------------------------------------------------------
// Stage 3 (fused tables + out3 + loss). Replaces k_tables/k_scatter/k_loss.
// Every block redundantly computes the transfer tables from ghist (6KB
// L2-hot read + wave scan + 8-step binary search; identical float compares
// to the verified k_tables), then streams out3 densely:
//   out3[p] = marked(p) ? table[bin8(out1[p])] : out1[p]
// accumulating loss = mean|out2 - out3| in the same pass. This converts the
// old scattered 4B RMW rewrite of out3 (~99.8% of lines dirtied anyway) into
// one coalesced float4 write pass and removes the 25MB loss re-read.
// ---------------------------------------------------------------------------
__global__ __launch_bounds__(384)
void k_finalize(const uint4* __restrict__ ghist4,
                const unsigned int* __restrict__ bm,
                const float4* __restrict__ out1v,
                const float4* __restrict__ out2v,
                float4* __restrict__ out3v,
                float* __restrict__ loss)
{
    __shared__ float cdf[6][NB];     // rows 0-2: cdf_dst, rows 3-5: cdf_ref
    __shared__ float tl[3 * NB];     // tables, PRE-DIVIDED by 255
    __shared__ float ws[6];
    int t = threadIdx.x;
    int wave = t >> 6, lane = t & 63;

    // --- per-block table compute (6 waves, one histogram row each) ---
    uint4 v = ghist4[wave * 64 + lane];
    unsigned int s0 = v.x;
    unsigned int s1 = s0 + v.y;
    unsigned int s2 = s1 + v.z;
    unsigned int s3 = s2 + v.w;

    unsigned int scan = s3;
#pragma unroll
    for (int off = 1; off < 64; off <<= 1) {
        unsigned int u = (unsigned int)__shfl_up((int)scan, off, 64);
        if (lane >= off) scan += u;
    }
    unsigned int prefix = scan - s3;
    unsigned int total  = (unsigned int)__shfl((int)scan, 63, 64);
    float ft = (float)total;

    cdf[wave][lane * 4 + 0] = (float)(prefix + s0) / ft;
    cdf[wave][lane * 4 + 1] = (float)(prefix + s1) / ft;
    cdf[wave][lane * 4 + 2] = (float)(prefix + s2) / ft;
    cdf[wave][lane * 4 + 3] = (float)(prefix + s3) / ft;
    __syncthreads();

    if (t < NB) {
#pragma unroll
        for (int c = 0; c < 3; ++c) {
            float r = cdf[c][t];
            const float* cr = cdf[3 + c];
            int lo = 1, hi = NB - 1;
#pragma unroll
            for (int it = 0; it < 8; ++it) {
                int mid = (lo + hi) >> 1;
                if (cr[mid] >= r) hi = mid; else lo = mid + 1;
            }
            int jstar = lo - 1;
            int tab = (jstar == 0 && cr[0] > r) ? t : (jstar + 1);
            if (t == NB - 1) tab = NB - 1;
            tl[c * NB + t] = (float)tab / 255.0f;
        }
    }
    __syncthreads();

    // --- dense out3 + loss streaming pass ---
    float s = 0.0f;
    const int n4 = HH / 4;
    for (int k = blockIdx.x * blockDim.x + t; k < n4; k += gridDim.x * blockDim.x) {
        unsigned int w = bm[k >> 3];
        unsigned int nib = (w >> ((k & 7) * 4)) & 0xFu;   // flags for pixels 4k..4k+3
#pragma unroll
        for (int c = 0; c < 3; ++c) {
            float4 a = out1v[c * n4 + k];
            float4 b = out2v[c * n4 + k];
            float4 o;
            o.x = (nib & 1u) ? tl[c * NB + bin8(a.x)] : a.x;
            o.y = (nib & 2u) ? tl[c * NB + bin8(a.y)] : a.y;
            o.z = (nib & 4u) ? tl[c * NB + bin8(a.z)] : a.z;
            o.w = (nib & 8u) ? tl[c * NB + bin8(a.w)] : a.w;
            out3v[c * n4 + k] = o;
            s += fabsf(b.x - o.x) + fabsf(b.y - o.y) + fabsf(b.z - o.z) + fabsf(b.w - o.w);
        }
    }
#pragma unroll
    for (int off = 32; off > 0; off >>= 1) s += __shfl_down(s, off);
    if (lane == 0) ws[wave] = s;
    __syncthreads();
    if (t == 0) {
        float tsum = ws[0] + ws[1] + ws[2] + ws[3] + ws[4] + ws[5];
        atomicAdd(loss, tsum * (1.0f / (float)CHW));
    }
}

extern "C" void kernel_launch(void* const* d_in, const int* in_sizes, int n_in,
                              void* d_out, int out_size, void* d_ws, size_t ws_size,
                              hipStream_t stream)
{
    const float* inp  = (const float*)d_in[0];
    const float* tar  = (const float*)d_in[1];
    const float* rfp  = (const float*)d_in[2];
    const float* msrc = (const float*)d_in[3];
    const float* mtar = (const float*)d_in[4];
    // d_in[5] = target_data_eye (unused by the reference computation)
    const int* i0 = (const int*)d_in[6];
    const int* i1 = (const int*)d_in[7];
    const int* i2 = (const int*)d_in[8];
    const int* i3 = (const int*)d_in[9];
    int n = in_sizes[6];

    float* out0 = (float*)d_out;
    float* out1 = out0 + CHW;
    float* out2 = out1 + CHW;
    float* out3 = out2 + CHW;
    float* loss = out3 + CHW;

    // workspace layout
    unsigned int* ghist  = (unsigned int*)d_ws;                      // [0, 6144): 1536 u32
    unsigned int* bm     = (unsigned int*)((char*)d_ws + 8192);      // [8192, 139264): 32768 u32 bitmap (128 KB)
    unsigned int* pk_dst = (unsigned int*)((char*)d_ws + 139264);    // HH u32 (4 MB)
    unsigned int* pk_ref = pk_dst + HH;                              // HH u32 (4 MB)

    k_elementwise<<<(HH / 4 + 255) / 256, 256, 0, stream>>>(
        (const float4*)inp, (const float4*)tar, (const float4*)rfp,
        (const float4*)msrc, (const float4*)mtar,
        (float4*)out0, (float4*)out1, (float4*)out2,
        (uint4*)pk_dst, (uint4*)pk_ref, ghist, bm, loss);

    k_hist<<<HIST_BLOCKS, 512, 0, stream>>>(pk_dst, pk_ref, i0, i1, i2, i3, ghist, bm, n);

    k_finalize<<<FIN_BLOCKS, 384, 0, stream>>>(
        (const uint4*)ghist, bm, (const float4*)out1, (const float4*)out2,
        (float4*)out3, loss);
}